// Round 1
// baseline (232.097 us; speedup 1.0000x reference)
//
#include <hip/hip_runtime.h>
#include <math.h>

#define DIM 1024
#define NQ 10
#define NL 4
#define SEQ 512
#define NROWS 4096
#define PRED 96

// ---------------------------------------------------------------------------
// Kernel 1: h = x @ W_in^T + b_in + 1e-6
// x: (4096, 512) row-major, W_in: (1024, 512) row-major, h: (4096, 1024)
// 128x64 block tile, BK=16, 256 threads, 8x4 per-thread microtile.
// ---------------------------------------------------------------------------
#define BM 128
#define BN 64
#define BK 16

__global__ __launch_bounds__(256)
void gemm_h_kernel(const float* __restrict__ x, const float* __restrict__ Wi,
                   const float* __restrict__ b_in, float* __restrict__ h)
{
    // K-major-transposed tiles so inner loop reads are contiguous float4s.
    // Pad +4 keeps float4 (16B) alignment: (BM+4)*4B and (BN+4)*4B are 16B multiples.
    __shared__ float As[BK][BM + 4];
    __shared__ float Bs[BK][BN + 4];

    const int tid = threadIdx.x;
    const int bm = blockIdx.x;   // 0..31
    const int bn = blockIdx.y;   // 0..15
    const int tx = tid & 15;     // col group: 4 cols
    const int ty = tid >> 4;     // row group: 8 rows

    float acc[8][4];
#pragma unroll
    for (int i = 0; i < 8; ++i)
#pragma unroll
        for (int j = 0; j < 4; ++j) acc[i][j] = 0.f;

    const float* xa = x + (size_t)(bm * BM) * SEQ;
    const float* wb = Wi + (size_t)(bn * BN) * SEQ;

    for (int k0 = 0; k0 < SEQ; k0 += BK) {
        // A tile: 128x16 floats = 512 float4s; 256 threads -> 2 each
#pragma unroll
        for (int i = 0; i < 2; ++i) {
            int f = tid + i * 256;
            int r = f >> 2, c4 = f & 3;
            float4 v = *(const float4*)(xa + (size_t)r * SEQ + k0 + c4 * 4);
            As[c4 * 4 + 0][r] = v.x; As[c4 * 4 + 1][r] = v.y;
            As[c4 * 4 + 2][r] = v.z; As[c4 * 4 + 3][r] = v.w;
        }
        // B tile: 64x16 floats = 256 float4s; 1 each
        {
            int r = tid >> 2, c4 = tid & 3;
            float4 v = *(const float4*)(wb + (size_t)r * SEQ + k0 + c4 * 4);
            Bs[c4 * 4 + 0][r] = v.x; Bs[c4 * 4 + 1][r] = v.y;
            Bs[c4 * 4 + 2][r] = v.z; Bs[c4 * 4 + 3][r] = v.w;
        }
        __syncthreads();
#pragma unroll
        for (int kk = 0; kk < BK; ++kk) {
            float4 a0 = *(const float4*)&As[kk][ty * 8];
            float4 a1 = *(const float4*)&As[kk][ty * 8 + 4];
            float4 b4 = *(const float4*)&Bs[kk][tx * 4];
            float a[8] = {a0.x, a0.y, a0.z, a0.w, a1.x, a1.y, a1.z, a1.w};
            float b[4] = {b4.x, b4.y, b4.z, b4.w};
#pragma unroll
            for (int i = 0; i < 8; ++i)
#pragma unroll
                for (int j = 0; j < 4; ++j)
                    acc[i][j] = fmaf(a[i], b[j], acc[i][j]);
        }
        __syncthreads();
    }

#pragma unroll
    for (int i = 0; i < 8; ++i) {
        int row = bm * BM + ty * 8 + i;
        int col = bn * BN + tx * 4;
        float4 o;
        o.x = acc[i][0] + b_in[col + 0] + 1e-6f;
        o.y = acc[i][1] + b_in[col + 1] + 1e-6f;
        o.z = acc[i][2] + b_in[col + 2] + 1e-6f;
        o.w = acc[i][3] + b_in[col + 3] + 1e-6f;
        *(float4*)(h + (size_t)row * DIM + col) = o;
    }
}

// ---------------------------------------------------------------------------
// Kernel 2: per-row normalize -> 4x(10 gates + perm) -> expvals -> W_out
// One block of 512 threads per row; psi (1024 complex fp32) lives in LDS.
// ---------------------------------------------------------------------------
__global__ __launch_bounds__(512)
void circuit_kernel(const float* __restrict__ h, const float* __restrict__ qw,
                    const float* __restrict__ W_out, const float* __restrict__ b_out,
                    float* __restrict__ out)
{
    __shared__ float2 psi[DIM];
    __shared__ float gm[NL * NQ][8];
    __shared__ float red[16];
    __shared__ float evp[8][NQ];
    __shared__ float evs[NQ];

    const int tid = threadIdx.x;
    const int row = blockIdx.x;
    const int lane = tid & 63;
    const int wid = tid >> 6;

    // Precompute all 40 gate matrices into LDS.
    // m00 = conj(ep)*c, m01 = -em*s, m10 = conj(em)*s, m11 = ep*c
    // ep = exp(0.5i(phi+omega)), em = exp(0.5i(phi-omega))
    if (tid < NL * NQ) {
        float phi = qw[tid * 3 + 0], theta = qw[tid * 3 + 1], omega = qw[tid * 3 + 2];
        float ch = cosf(theta * 0.5f), sh = sinf(theta * 0.5f);
        float a = 0.5f * (phi + omega), b = 0.5f * (phi - omega);
        float ca = cosf(a), sa = sinf(a);
        float cb = cosf(b), sb = sinf(b);
        gm[tid][0] =  ch * ca;  gm[tid][1] = -ch * sa;   // m00
        gm[tid][2] = -sh * cb;  gm[tid][3] = -sh * sb;   // m01
        gm[tid][4] =  sh * cb;  gm[tid][5] = -sh * sb;   // m10
        gm[tid][6] =  ch * ca;  gm[tid][7] =  ch * sa;   // m11
    }

    // Load h row (2 floats/thread), reduce sum of squares -> 1/norm.
    float2 v = ((const float2*)(h + (size_t)row * DIM))[tid];
    float ss = v.x * v.x + v.y * v.y;
#pragma unroll
    for (int o = 32; o > 0; o >>= 1) ss += __shfl_down(ss, o, 64);
    if (lane == 0) red[wid] = ss;
    __syncthreads();
    if (tid == 0) {
        float t = 0.f;
        for (int i = 0; i < 8; ++i) t += red[i];
        red[8] = 1.0f / sqrtf(t);
    }
    __syncthreads();
    const float rinv = red[8];
    psi[2 * tid]     = make_float2(v.x * rinv, 0.f);
    psi[2 * tid + 1] = make_float2(v.y * rinv, 0.f);
    __syncthreads();

    // Circuit: NL layers of 10 single-qubit gates + a basis permutation.
    for (int l = 0; l < NL; ++l) {
#pragma unroll
        for (int w = 0; w < NQ; ++w) {
            const float* m = gm[l * NQ + w];
            float m00r = m[0], m00i = m[1], m01r = m[2], m01i = m[3];
            float m10r = m[4], m10i = m[5], m11r = m[6], m11i = m[7];
            int mask = 1 << (9 - w);
            int lo = tid & (mask - 1);
            int s0 = ((tid ^ lo) << 1) | lo;   // insert 0 at bit (9-w)
            int s1 = s0 | mask;
            float2 a0 = psi[s0], a1 = psi[s1];
            float2 n0, n1;
            n0.x = m00r * a0.x - m00i * a0.y + m01r * a1.x - m01i * a1.y;
            n0.y = m00r * a0.y + m00i * a0.x + m01r * a1.y + m01i * a1.x;
            n1.x = m10r * a0.x - m10i * a0.y + m11r * a1.x - m11i * a1.y;
            n1.y = m10r * a0.y + m10i * a0.x + m11r * a1.y + m11i * a1.x;
            psi[s0] = n0; psi[s1] = n1;
            __syncthreads();
        }
        // Permutation: psi_new[s] = psi_old[perm(s)],
        // perm(s) = g0(g1(...g9(s))) with g_c(s) = s ^ (bit(9-c) << (9-(c+r)%10))
        int r = l % (NQ - 1) + 1;
        int p0 = tid, p1 = tid + 512;
#pragma unroll
        for (int c = 9; c >= 0; --c) {
            int t = (c + r) % NQ;
            p0 ^= ((p0 >> (9 - c)) & 1) << (9 - t);
            p1 ^= ((p1 >> (9 - c)) & 1) << (9 - t);
        }
        float2 t0 = psi[p0], t1 = psi[p1];
        __syncthreads();
        psi[tid] = t0; psi[tid + 512] = t1;
        __syncthreads();
    }

    // Expvals: ev[k] = sum_s (1-2*bit_k(s)) * |psi_s|^2   (psi normalized)
    float2 v0 = psi[tid], v1 = psi[tid + 512];
    float q0 = v0.x * v0.x + v0.y * v0.y;
    float q1 = v1.x * v1.x + v1.y * v1.y;
    float ev[NQ];
#pragma unroll
    for (int k = 0; k < NQ; ++k) {
        int shft = 9 - k;
        float t0 = ((tid >> shft) & 1) ? -q0 : q0;
        float t1 = (((tid + 512) >> shft) & 1) ? -q1 : q1;
        ev[k] = t0 + t1;
    }
#pragma unroll
    for (int k = 0; k < NQ; ++k)
#pragma unroll
        for (int o = 32; o > 0; o >>= 1) ev[k] += __shfl_down(ev[k], o, 64);
    if (lane == 0)
#pragma unroll
        for (int k = 0; k < NQ; ++k) evp[wid][k] = ev[k];
    __syncthreads();
    if (tid < NQ) {
        float t = 0.f;
        for (int wv = 0; wv < 8; ++wv) t += evp[wv][tid];
        evs[tid] = t;
    }
    __syncthreads();

    // out[row, j] = b_out[j] + sum_k W_out[j,k] * evs[k]
    if (tid < PRED) {
        float o = b_out[tid];
#pragma unroll
        for (int k = 0; k < NQ; ++k) o = fmaf(W_out[tid * NQ + k], evs[k], o);
        out[(size_t)row * PRED + tid] = o;
    }
}

extern "C" void kernel_launch(void* const* d_in, const int* in_sizes, int n_in,
                              void* d_out, int out_size, void* d_ws, size_t ws_size,
                              hipStream_t stream) {
    const float* x     = (const float*)d_in[0];
    const float* W_in  = (const float*)d_in[1];
    const float* b_in  = (const float*)d_in[2];
    const float* qw    = (const float*)d_in[3];
    const float* W_out = (const float*)d_in[4];
    const float* b_out = (const float*)d_in[5];
    float* out = (float*)d_out;
    float* h = (float*)d_ws;   // 4096*1024*4 = 16 MB scratch, fully overwritten

    dim3 ggrid(NROWS / BM, DIM / BN);
    gemm_h_kernel<<<ggrid, 256, 0, stream>>>(x, W_in, b_in, h);
    circuit_kernel<<<NROWS, 512, 0, stream>>>(h, qw, W_out, b_out, out);
}

// Round 2
// 121.992 us; speedup vs baseline: 1.9026x; 1.9026x over previous
//
#include <hip/hip_runtime.h>
#include <math.h>

#define DIM 1024
#define NQ 10
#define NL 4
#define SEQ 512
#define NROWS 4096
#define PRED 96

typedef unsigned short ushort_t;
typedef unsigned int uint_t;
using short8  = __attribute__((ext_vector_type(8))) short;
using float4v = __attribute__((ext_vector_type(4))) float;

__device__ inline uint_t f2bf1(float f) {
    uint_t u = __float_as_uint(f);
    return (u + 0x7fffu + ((u >> 16) & 1u)) >> 16;
}
__device__ inline float bf2f(uint_t s) { return __uint_as_float(s << 16); }

// ---------------------------------------------------------------------------
// Kernel 1: apply the circuit to the 512 columns of W_in plus the bias vector.
// Block j < 512: input v_k = W_in[k][j]; block 512: v_k = b_in[k] + 1e-6.
// Outputs (no normalization — circuit is linear, norm handled at the end):
//   j<512:  Crt_r[s][j], Crt_i[s][j]  (bf16, s-major: B^T layout for the GEMM)
//   j==512: dr[s], di[s]              (fp32 bias vectors)
// ---------------------------------------------------------------------------
__global__ __launch_bounds__(512)
void circuit_cols_kernel(const float* __restrict__ Wi, const float* __restrict__ b_in,
                         const float* __restrict__ qw,
                         ushort_t* __restrict__ Crt_r, ushort_t* __restrict__ Crt_i,
                         float* __restrict__ dr, float* __restrict__ di)
{
    __shared__ float2 psi[DIM];
    __shared__ float gm[NL * NQ][8];

    const int tid = threadIdx.x;
    const int j = blockIdx.x;

    if (tid < NL * NQ) {
        float phi = qw[tid * 3 + 0], theta = qw[tid * 3 + 1], omega = qw[tid * 3 + 2];
        float ch = cosf(theta * 0.5f), sh = sinf(theta * 0.5f);
        float a = 0.5f * (phi + omega), b = 0.5f * (phi - omega);
        float ca = cosf(a), sa = sinf(a);
        float cb = cosf(b), sb = sinf(b);
        gm[tid][0] =  ch * ca;  gm[tid][1] = -ch * sa;   // m00
        gm[tid][2] = -sh * cb;  gm[tid][3] = -sh * sb;   // m01
        gm[tid][4] =  sh * cb;  gm[tid][5] = -sh * sb;   // m10
        gm[tid][6] =  ch * ca;  gm[tid][7] =  ch * sa;   // m11
    }

    float v0, v1;
    if (j < SEQ) {
        v0 = Wi[(size_t)(2 * tid) * SEQ + j];
        v1 = Wi[(size_t)(2 * tid + 1) * SEQ + j];
    } else {
        v0 = b_in[2 * tid] + 1e-6f;
        v1 = b_in[2 * tid + 1] + 1e-6f;
    }
    psi[2 * tid]     = make_float2(v0, 0.f);
    psi[2 * tid + 1] = make_float2(v1, 0.f);
    __syncthreads();

    for (int l = 0; l < NL; ++l) {
#pragma unroll
        for (int w = 0; w < NQ; ++w) {
            const float* m = gm[l * NQ + w];
            float m00r = m[0], m00i = m[1], m01r = m[2], m01i = m[3];
            float m10r = m[4], m10i = m[5], m11r = m[6], m11i = m[7];
            int mask = 1 << (9 - w);
            int lo = tid & (mask - 1);
            int s0 = ((tid ^ lo) << 1) | lo;
            int s1 = s0 | mask;
            float2 a0 = psi[s0], a1 = psi[s1];
            float2 n0, n1;
            n0.x = m00r * a0.x - m00i * a0.y + m01r * a1.x - m01i * a1.y;
            n0.y = m00r * a0.y + m00i * a0.x + m01r * a1.y + m01i * a1.x;
            n1.x = m10r * a0.x - m10i * a0.y + m11r * a1.x - m11i * a1.y;
            n1.y = m10r * a0.y + m10i * a0.x + m11r * a1.y + m11i * a1.x;
            psi[s0] = n0; psi[s1] = n1;
            __syncthreads();
        }
        int r = l % (NQ - 1) + 1;
        int p0 = tid, p1 = tid + 512;
#pragma unroll
        for (int c = 9; c >= 0; --c) {
            int t = (c + r) % NQ;
            p0 ^= ((p0 >> (9 - c)) & 1) << (9 - t);
            p1 ^= ((p1 >> (9 - c)) & 1) << (9 - t);
        }
        float2 t0 = psi[p0], t1 = psi[p1];
        __syncthreads();
        psi[tid] = t0; psi[tid + 512] = t1;
        __syncthreads();
    }

    float2 o0 = psi[tid], o1 = psi[tid + 512];
    if (j < SEQ) {
        Crt_r[(size_t)tid * SEQ + j]         = (ushort_t)f2bf1(o0.x);
        Crt_i[(size_t)tid * SEQ + j]         = (ushort_t)f2bf1(o0.y);
        Crt_r[(size_t)(tid + 512) * SEQ + j] = (ushort_t)f2bf1(o1.x);
        Crt_i[(size_t)(tid + 512) * SEQ + j] = (ushort_t)f2bf1(o1.y);
    } else {
        dr[tid] = o0.x;        di[tid] = o0.y;
        dr[tid + 512] = o1.x;  di[tid + 512] = o1.y;
    }
}

// ---------------------------------------------------------------------------
// Kernel 2: fused MFMA GEMM + probs + signed partial reduction.
// z_r + i z_i = (Crt + 0) @ x_row + d;  x split hi/lo bf16 for accuracy.
// Tile: BM=128 rows x 64 complex cols, 256 threads (4 waves), BK=32.
// Epilogue: p = zr^2 + zi^2 -> LDS -> per-(row, half-tile) partials:
//   [norm, e_k for k=4..9]  (k=0..3 signs are constant per n-block).
// ---------------------------------------------------------------------------
#define GBM 128
#define GBNC 64
#define GBK 32
#define LDA 40   // ushort stride for LDS tiles (pad: 2-way bank alias only)
#define LDP 65   // float stride for probs tile

__global__ __launch_bounds__(256)
void gemm_fused_kernel(const float* __restrict__ x,
                       const ushort_t* __restrict__ Crt_r, const ushort_t* __restrict__ Crt_i,
                       const float* __restrict__ dr, const float* __restrict__ di,
                       float* __restrict__ part)
{
    __shared__ __align__(16) char lds[GBM * LDP * 4];  // 33280 B; staging needs 30720 B
    ushort_t* Ash = (ushort_t*)lds;            // 128*40
    ushort_t* Asl = Ash + GBM * LDA;           // 128*40
    ushort_t* Bsr = Asl + GBM * LDA;           // 64*40
    ushort_t* Bsi = Bsr + GBNC * LDA;          // 64*40
    float*    Ps  = (float*)lds;               // reused after K-loop
    __shared__ float drs[GBNC], dis[GBNC];

    const int tid = threadIdx.x;
    const int bm = blockIdx.x, bn = blockIdx.y;
    const int lane = tid & 63, wv = tid >> 6;
    const int n0 = bn * GBNC;

    if (tid < GBNC) { drs[tid] = dr[n0 + tid]; dis[tid] = di[n0 + tid]; }

    float4v accr[2][4], acci[2][4];
#pragma unroll
    for (int a = 0; a < 2; ++a)
#pragma unroll
        for (int b = 0; b < 4; ++b) { accr[a][b] = (float4v)0.f; acci[a][b] = (float4v)0.f; }

    // A staging: thread -> row sr (0..127), k offset ko (0 or 16)
    const int sr = tid >> 1, ko = (tid & 1) * 16;
    const float* xa = x + (size_t)(bm * GBM + sr) * SEQ + ko;
    // B staging: threads 0-127 real, 128-255 imag; 16 bf16 each
    const int bsel = tid >> 7;
    const int nr = (tid & 127) >> 1;
    const int bko = (tid & 1) * 16;
    const ushort_t* bsrc = (bsel ? Crt_i : Crt_r) + (size_t)(n0 + nr) * SEQ + bko;
    ushort_t* bdst = (bsel ? Bsi : Bsr) + nr * LDA + bko;

    const int fm = lane & 15, kq = (lane >> 4) * 8;
    const int wrow = wv * 32;

    for (int k0 = 0; k0 < SEQ; k0 += GBK) {
        // --- stage A (fp32 -> bf16 hi + lo) ---
        float fv[16];
        *(float4*)&fv[0]  = *(const float4*)(xa + k0);
        *(float4*)&fv[4]  = *(const float4*)(xa + k0 + 4);
        *(float4*)&fv[8]  = *(const float4*)(xa + k0 + 8);
        *(float4*)&fv[12] = *(const float4*)(xa + k0 + 12);
        uint_t ph[8], pl[8];
#pragma unroll
        for (int i = 0; i < 8; ++i) {
            uint_t h0 = f2bf1(fv[2 * i]), h1 = f2bf1(fv[2 * i + 1]);
            float l0 = fv[2 * i] - bf2f(h0), l1 = fv[2 * i + 1] - bf2f(h1);
            ph[i] = h0 | (h1 << 16);
            pl[i] = f2bf1(l0) | (f2bf1(l1) << 16);
        }
        *(uint4*)(Ash + sr * LDA + ko)     = make_uint4(ph[0], ph[1], ph[2], ph[3]);
        *(uint4*)(Ash + sr * LDA + ko + 8) = make_uint4(ph[4], ph[5], ph[6], ph[7]);
        *(uint4*)(Asl + sr * LDA + ko)     = make_uint4(pl[0], pl[1], pl[2], pl[3]);
        *(uint4*)(Asl + sr * LDA + ko + 8) = make_uint4(pl[4], pl[5], pl[6], pl[7]);
        // --- stage B (bf16 passthrough) ---
        uint4 b0 = *(const uint4*)(bsrc + k0);
        uint4 b1 = *(const uint4*)(bsrc + k0 + 8);
        *(uint4*)bdst       = b0;
        *(uint4*)(bdst + 8) = b1;
        __syncthreads();

        short8 ah0 = *(short8*)(Ash + (wrow + fm) * LDA + kq);
        short8 ah1 = *(short8*)(Ash + (wrow + 16 + fm) * LDA + kq);
        short8 al0 = *(short8*)(Asl + (wrow + fm) * LDA + kq);
        short8 al1 = *(short8*)(Asl + (wrow + 16 + fm) * LDA + kq);
#pragma unroll
        for (int nt = 0; nt < 4; ++nt) {
            short8 br = *(short8*)(Bsr + (nt * 16 + fm) * LDA + kq);
            short8 bi = *(short8*)(Bsi + (nt * 16 + fm) * LDA + kq);
            accr[0][nt] = __builtin_amdgcn_mfma_f32_16x16x32_bf16(ah0, br, accr[0][nt], 0, 0, 0);
            accr[1][nt] = __builtin_amdgcn_mfma_f32_16x16x32_bf16(ah1, br, accr[1][nt], 0, 0, 0);
            acci[0][nt] = __builtin_amdgcn_mfma_f32_16x16x32_bf16(ah0, bi, acci[0][nt], 0, 0, 0);
            acci[1][nt] = __builtin_amdgcn_mfma_f32_16x16x32_bf16(ah1, bi, acci[1][nt], 0, 0, 0);
            accr[0][nt] = __builtin_amdgcn_mfma_f32_16x16x32_bf16(al0, br, accr[0][nt], 0, 0, 0);
            accr[1][nt] = __builtin_amdgcn_mfma_f32_16x16x32_bf16(al1, br, accr[1][nt], 0, 0, 0);
            acci[0][nt] = __builtin_amdgcn_mfma_f32_16x16x32_bf16(al0, bi, acci[0][nt], 0, 0, 0);
            acci[1][nt] = __builtin_amdgcn_mfma_f32_16x16x32_bf16(al1, bi, acci[1][nt], 0, 0, 0);
        }
        __syncthreads();
    }

    // --- epilogue: p = (zr)^2 + (zi)^2 into LDS ---
    const int rq = (lane >> 4) * 4;
#pragma unroll
    for (int mt = 0; mt < 2; ++mt)
#pragma unroll
        for (int nt = 0; nt < 4; ++nt) {
            float drv = drs[nt * 16 + fm], div = dis[nt * 16 + fm];
#pragma unroll
            for (int reg = 0; reg < 4; ++reg) {
                int lrow = wrow + mt * 16 + rq + reg;
                float zr = accr[mt][nt][reg] + drv;
                float zi = acci[mt][nt][reg] + div;
                Ps[lrow * LDP + nt * 16 + fm] = zr * zr + zi * zi;
            }
        }
    __syncthreads();

    // --- signed partial reduction over the block's 64 cols (low 6 bits of s) ---
    {
        const int row = tid >> 1, hh = tid & 1;
        const float* pr = Ps + row * LDP + hh * 32;
        float nrm = 0.f, e0 = 0.f, e1 = 0.f, e2 = 0.f, e3 = 0.f, e4 = 0.f, e5 = 0.f;
#pragma unroll
        for (int i = 0; i < 32; ++i) {
            float p = pr[i];
            int c = hh * 32 + i;
            nrm += p;
            e0 += ((c >> 5) & 1) ? -p : p;   // k=4
            e1 += ((c >> 4) & 1) ? -p : p;   // k=5
            e2 += ((c >> 3) & 1) ? -p : p;   // k=6
            e3 += ((c >> 2) & 1) ? -p : p;   // k=7
            e4 += ((c >> 1) & 1) ? -p : p;   // k=8
            e5 += (c & 1) ? -p : p;          // k=9
        }
        size_t base = ((size_t)(bn * 2 + hh) * NROWS + bm * GBM + row) * 8;
        part[base + 0] = nrm;
        part[base + 1] = e0; part[base + 2] = e1; part[base + 3] = e2;
        part[base + 4] = e3; part[base + 5] = e4; part[base + 6] = e5;
    }
}

// ---------------------------------------------------------------------------
// Kernel 3: combine 32 partials per row, derive k=0..3 from block signs,
// normalize, apply W_out epilogue.
// ---------------------------------------------------------------------------
__global__ __launch_bounds__(128)
void finalize_kernel(const float* __restrict__ part, const float* __restrict__ W_out,
                     const float* __restrict__ b_out, float* __restrict__ out)
{
    __shared__ float sred[32][8];
    __shared__ float evf[12];
    const int row = blockIdx.x, tid = threadIdx.x;

    if (tid < 32) {
        const float* p = part + ((size_t)tid * NROWS + row) * 8;
        *(float4*)&sred[tid][0] = *(const float4*)p;
        *(float4*)&sred[tid][4] = *(const float4*)(p + 4);
    }
    __syncthreads();
    if (tid == 0) {
        float nrm = 0.f, ev[10];
#pragma unroll
        for (int k = 0; k < 10; ++k) ev[k] = 0.f;
        for (int pb = 0; pb < 32; ++pb) {
            int bnn = pb >> 1;   // n0 = bnn*64; s bits 9..6 = bits 3..0 of bnn
            float n0 = sred[pb][0];
            nrm += n0;
            ev[0] += ((bnn >> 3) & 1) ? -n0 : n0;
            ev[1] += ((bnn >> 2) & 1) ? -n0 : n0;
            ev[2] += ((bnn >> 1) & 1) ? -n0 : n0;
            ev[3] += (bnn & 1) ? -n0 : n0;
#pragma unroll
            for (int k = 4; k < 10; ++k) ev[k] += sred[pb][k - 3];
        }
        float inv = 1.0f / nrm;
#pragma unroll
        for (int k = 0; k < 10; ++k) evf[k] = ev[k] * inv;
    }
    __syncthreads();
    if (tid < PRED) {
        float o = b_out[tid];
#pragma unroll
        for (int k = 0; k < NQ; ++k) o = fmaf(W_out[tid * NQ + k], evf[k], o);
        out[(size_t)row * PRED + tid] = o;
    }
}

extern "C" void kernel_launch(void* const* d_in, const int* in_sizes, int n_in,
                              void* d_out, int out_size, void* d_ws, size_t ws_size,
                              hipStream_t stream) {
    const float* x     = (const float*)d_in[0];
    const float* W_in  = (const float*)d_in[1];
    const float* b_in  = (const float*)d_in[2];
    const float* qw    = (const float*)d_in[3];
    const float* W_out = (const float*)d_in[4];
    const float* b_out = (const float*)d_in[5];
    float* out = (float*)d_out;

    char* w = (char*)d_ws;
    ushort_t* Crt_r = (ushort_t*)w;                         // 1024*512*2 = 1 MB
    ushort_t* Crt_i = (ushort_t*)(w + (1u << 20));          // 1 MB
    float* dr = (float*)(w + 2 * (1u << 20));               // 4 KB
    float* di = dr + DIM;                                   // 4 KB
    float* part = (float*)(w + 3 * (1u << 20));             // 32*4096*8*4 = 4 MB

    circuit_cols_kernel<<<SEQ + 1, 512, 0, stream>>>(W_in, b_in, qw, Crt_r, Crt_i, dr, di);
    dim3 g2(NROWS / GBM, DIM / GBNC);
    gemm_fused_kernel<<<g2, 256, 0, stream>>>(x, Crt_r, Crt_i, dr, di, part);
    finalize_kernel<<<NROWS, 128, 0, stream>>>(part, W_out, b_out, out);
}

// Round 3
// 114.653 us; speedup vs baseline: 2.0243x; 1.0640x over previous
//
#include <hip/hip_runtime.h>
#include <math.h>

#define DIM 1024
#define NQ 10
#define NL 4
#define SEQ 512
#define NROWS 4096
#define PRED 96

typedef unsigned short ushort_t;
typedef unsigned int uint_t;
using half8   = __attribute__((ext_vector_type(8))) _Float16;
using float4v = __attribute__((ext_vector_type(4))) float;

__device__ inline ushort_t f2h(float f) { _Float16 h = (_Float16)f; return *(ushort_t*)&h; }
__device__ inline uint_t pkh(float a, float b) {
    _Float16 ha = (_Float16)a, hb = (_Float16)b;   // RTE via v_cvt_f16_f32
    return (uint_t)(*(ushort_t*)&ha) | ((uint_t)(*(ushort_t*)&hb) << 16);
}

// ---------------------------------------------------------------------------
// Kernel 1: apply the circuit to the 512 columns of W_in plus the bias vector.
// Block j < 512: input v_k = W_in[k][j]; block 512: v_k = b_in[k] + 1e-6.
// Outputs: j<512: Crt_r/Crt_i[s][j] (f16, s-major = B^T layout for the GEMM);
//          j==512: dr[s], di[s] (fp32 bias vectors).  Circuit is linear and
//          norm-preserving, so normalization is deferred to the epilogue.
// ---------------------------------------------------------------------------
__global__ __launch_bounds__(512)
void circuit_cols_kernel(const float* __restrict__ Wi, const float* __restrict__ b_in,
                         const float* __restrict__ qw,
                         ushort_t* __restrict__ Crt_r, ushort_t* __restrict__ Crt_i,
                         float* __restrict__ dr, float* __restrict__ di)
{
    __shared__ float2 psi[DIM];
    __shared__ float gm[NL * NQ][8];

    const int tid = threadIdx.x;
    const int j = blockIdx.x;

    if (tid < NL * NQ) {
        float phi = qw[tid * 3 + 0], theta = qw[tid * 3 + 1], omega = qw[tid * 3 + 2];
        float ch = cosf(theta * 0.5f), sh = sinf(theta * 0.5f);
        float a = 0.5f * (phi + omega), b = 0.5f * (phi - omega);
        float ca = cosf(a), sa = sinf(a);
        float cb = cosf(b), sb = sinf(b);
        gm[tid][0] =  ch * ca;  gm[tid][1] = -ch * sa;   // m00
        gm[tid][2] = -sh * cb;  gm[tid][3] = -sh * sb;   // m01
        gm[tid][4] =  sh * cb;  gm[tid][5] = -sh * sb;   // m10
        gm[tid][6] =  ch * ca;  gm[tid][7] =  ch * sa;   // m11
    }

    float v0, v1;
    if (j < SEQ) {
        v0 = Wi[(size_t)(2 * tid) * SEQ + j];
        v1 = Wi[(size_t)(2 * tid + 1) * SEQ + j];
    } else {
        v0 = b_in[2 * tid] + 1e-6f;
        v1 = b_in[2 * tid + 1] + 1e-6f;
    }
    psi[2 * tid]     = make_float2(v0, 0.f);
    psi[2 * tid + 1] = make_float2(v1, 0.f);
    __syncthreads();

    for (int l = 0; l < NL; ++l) {
#pragma unroll
        for (int w = 0; w < NQ; ++w) {
            const float* m = gm[l * NQ + w];
            float m00r = m[0], m00i = m[1], m01r = m[2], m01i = m[3];
            float m10r = m[4], m10i = m[5], m11r = m[6], m11i = m[7];
            int mask = 1 << (9 - w);
            int lo = tid & (mask - 1);
            int s0 = ((tid ^ lo) << 1) | lo;
            int s1 = s0 | mask;
            float2 a0 = psi[s0], a1 = psi[s1];
            float2 n0, n1;
            n0.x = m00r * a0.x - m00i * a0.y + m01r * a1.x - m01i * a1.y;
            n0.y = m00r * a0.y + m00i * a0.x + m01r * a1.y + m01i * a1.x;
            n1.x = m10r * a0.x - m10i * a0.y + m11r * a1.x - m11i * a1.y;
            n1.y = m10r * a0.y + m10i * a0.x + m11r * a1.y + m11i * a1.x;
            psi[s0] = n0; psi[s1] = n1;
            __syncthreads();
        }
        int r = l % (NQ - 1) + 1;
        int p0 = tid, p1 = tid + 512;
#pragma unroll
        for (int c = 9; c >= 0; --c) {
            int t = (c + r) % NQ;
            p0 ^= ((p0 >> (9 - c)) & 1) << (9 - t);
            p1 ^= ((p1 >> (9 - c)) & 1) << (9 - t);
        }
        float2 t0 = psi[p0], t1 = psi[p1];
        __syncthreads();
        psi[tid] = t0; psi[tid + 512] = t1;
        __syncthreads();
    }

    float2 o0 = psi[tid], o1 = psi[tid + 512];
    if (j < SEQ) {
        Crt_r[(size_t)tid * SEQ + j]         = f2h(o0.x);
        Crt_i[(size_t)tid * SEQ + j]         = f2h(o0.y);
        Crt_r[(size_t)(tid + 512) * SEQ + j] = f2h(o1.x);
        Crt_i[(size_t)(tid + 512) * SEQ + j] = f2h(o1.y);
    } else {
        dr[tid] = o0.x;        di[tid] = o0.y;
        dr[tid + 512] = o1.x;  di[tid + 512] = o1.y;
    }
}

// ---------------------------------------------------------------------------
// Kernel 2: fused f16-MFMA GEMM + probs + signed partial reduction.
// z = x @ C^T + d (complex).  Tile 128 rows x 64 complex cols, BK=32, 4 waves.
// f16 both sides: 16 MFMA/K-iter (vs 32 for bf16 hi/lo split), and C at f16
// carries 8x finer mantissa than bf16 -> error improves too.
// Epilogue: p = zr^2+zi^2 -> LDS -> per-(row, half) partials
//   [norm, e_k k=4..9] (s-bits 9..6 are constant per bn-block -> finalize).
// ---------------------------------------------------------------------------
#define GBM 128
#define GBNC 64
#define GBK 32
#define LDA 40   // half stride for LDS tiles
#define LDP 65   // float stride for probs tile

__global__ __launch_bounds__(256)
void gemm_fused_kernel(const float* __restrict__ x,
                       const ushort_t* __restrict__ Crt_r, const ushort_t* __restrict__ Crt_i,
                       const float* __restrict__ dr, const float* __restrict__ di,
                       float* __restrict__ part)
{
    __shared__ __align__(16) char lds[GBM * LDP * 4];  // 33280 B (probs tile is the max)
    ushort_t* Ash = (ushort_t*)lds;            // 128*40 halves = 10240 B
    ushort_t* Bsr = Ash + GBM * LDA;           // 64*40 = 5120 B
    ushort_t* Bsi = Bsr + GBNC * LDA;          // 64*40 = 5120 B
    float*    Ps  = (float*)lds;               // reused after K-loop
    __shared__ float drs[GBNC], dis[GBNC];

    const int tid = threadIdx.x;
    const int bm = blockIdx.x, bn = blockIdx.y;
    const int lane = tid & 63, wv = tid >> 6;
    const int n0 = bn * GBNC;

    if (tid < GBNC) { drs[tid] = dr[n0 + tid]; dis[tid] = di[n0 + tid]; }

    float4v accr[2][4], acci[2][4];
#pragma unroll
    for (int a = 0; a < 2; ++a)
#pragma unroll
        for (int b = 0; b < 4; ++b) { accr[a][b] = (float4v)0.f; acci[a][b] = (float4v)0.f; }

    // A staging: thread -> row sr (0..127), k offset ko (0 or 16); 16 floats -> 16 halves
    const int sr = tid >> 1, ko = (tid & 1) * 16;
    const float* xa = x + (size_t)(bm * GBM + sr) * SEQ + ko;
    // B staging: threads 0-127 real, 128-255 imag; 16 halves each
    const int bsel = tid >> 7;
    const int nr = (tid & 127) >> 1;
    const int bko = (tid & 1) * 16;
    const ushort_t* bsrc = (bsel ? Crt_i : Crt_r) + (size_t)(n0 + nr) * SEQ + bko;
    ushort_t* bdst = (bsel ? Bsi : Bsr) + nr * LDA + bko;

    const int fm = lane & 15, kq = (lane >> 4) * 8;
    const int wrow = wv * 32;

    for (int k0 = 0; k0 < SEQ; k0 += GBK) {
        float fv[16];
        *(float4*)&fv[0]  = *(const float4*)(xa + k0);
        *(float4*)&fv[4]  = *(const float4*)(xa + k0 + 4);
        *(float4*)&fv[8]  = *(const float4*)(xa + k0 + 8);
        *(float4*)&fv[12] = *(const float4*)(xa + k0 + 12);
        uint_t pk[8];
#pragma unroll
        for (int i = 0; i < 8; ++i) pk[i] = pkh(fv[2 * i], fv[2 * i + 1]);
        *(uint4*)(Ash + sr * LDA + ko)     = make_uint4(pk[0], pk[1], pk[2], pk[3]);
        *(uint4*)(Ash + sr * LDA + ko + 8) = make_uint4(pk[4], pk[5], pk[6], pk[7]);
        uint4 b0 = *(const uint4*)(bsrc + k0);
        uint4 b1 = *(const uint4*)(bsrc + k0 + 8);
        *(uint4*)bdst       = b0;
        *(uint4*)(bdst + 8) = b1;
        __syncthreads();

        half8 ah0 = *(half8*)(Ash + (wrow + fm) * LDA + kq);
        half8 ah1 = *(half8*)(Ash + (wrow + 16 + fm) * LDA + kq);
#pragma unroll
        for (int nt = 0; nt < 4; ++nt) {
            half8 br = *(half8*)(Bsr + (nt * 16 + fm) * LDA + kq);
            half8 bi = *(half8*)(Bsi + (nt * 16 + fm) * LDA + kq);
            accr[0][nt] = __builtin_amdgcn_mfma_f32_16x16x32_f16(ah0, br, accr[0][nt], 0, 0, 0);
            accr[1][nt] = __builtin_amdgcn_mfma_f32_16x16x32_f16(ah1, br, accr[1][nt], 0, 0, 0);
            acci[0][nt] = __builtin_amdgcn_mfma_f32_16x16x32_f16(ah0, bi, acci[0][nt], 0, 0, 0);
            acci[1][nt] = __builtin_amdgcn_mfma_f32_16x16x32_f16(ah1, bi, acci[1][nt], 0, 0, 0);
        }
        __syncthreads();
    }

    // --- epilogue: p = zr^2 + zi^2 into LDS ---
    const int rq = (lane >> 4) * 4;
#pragma unroll
    for (int mt = 0; mt < 2; ++mt)
#pragma unroll
        for (int nt = 0; nt < 4; ++nt) {
            float drv = drs[nt * 16 + fm], div = dis[nt * 16 + fm];
#pragma unroll
            for (int reg = 0; reg < 4; ++reg) {
                int lrow = wrow + mt * 16 + rq + reg;
                float zr = accr[mt][nt][reg] + drv;
                float zi = acci[mt][nt][reg] + div;
                Ps[lrow * LDP + nt * 16 + fm] = zr * zr + zi * zi;
            }
        }
    __syncthreads();

    // --- signed partials over this block's 64 cols (low 6 bits of s) ---
    {
        const int row = tid >> 1, hh = tid & 1;
        const float* pr = Ps + row * LDP + hh * 32;
        float nrm = 0.f, e0 = 0.f, e1 = 0.f, e2 = 0.f, e3 = 0.f, e4 = 0.f, e5 = 0.f;
#pragma unroll
        for (int i = 0; i < 32; ++i) {
            float p = pr[i];
            int c = hh * 32 + i;
            nrm += p;
            e0 += ((c >> 5) & 1) ? -p : p;   // k=4
            e1 += ((c >> 4) & 1) ? -p : p;   // k=5
            e2 += ((c >> 3) & 1) ? -p : p;   // k=6
            e3 += ((c >> 2) & 1) ? -p : p;   // k=7
            e4 += ((c >> 1) & 1) ? -p : p;   // k=8
            e5 += (c & 1) ? -p : p;          // k=9
        }
        // row-major partials: contiguous 1 KB per output row for finalize
        size_t base = ((size_t)(bm * GBM + row) * 32 + (bn * 2 + hh)) * 8;
        part[base + 0] = nrm;
        part[base + 1] = e0; part[base + 2] = e1; part[base + 3] = e2;
        part[base + 4] = e3; part[base + 5] = e4; part[base + 6] = e5;
    }
}

// ---------------------------------------------------------------------------
// Kernel 3: per-row wave-parallel combine of 32 partials + W_out epilogue.
// ---------------------------------------------------------------------------
__global__ __launch_bounds__(128)
void finalize_kernel(const float* __restrict__ part, const float* __restrict__ W_out,
                     const float* __restrict__ b_out, float* __restrict__ out)
{
    __shared__ float evf[16];
    const int row = blockIdx.x, tid = threadIdx.x;

    if (tid < 64) {
        float v[11];
        if (tid < 32) {
            const float* p = part + ((size_t)row * 32 + tid) * 8;
            float4 a = *(const float4*)p;
            float4 b = *(const float4*)(p + 4);
            float nrm = a.x;
            int bnn = tid >> 1;   // s bits 9..6 = bits 3..0 of bnn
            v[0] = nrm;
            v[1] = (bnn & 8) ? -nrm : nrm;
            v[2] = (bnn & 4) ? -nrm : nrm;
            v[3] = (bnn & 2) ? -nrm : nrm;
            v[4] = (bnn & 1) ? -nrm : nrm;
            v[5] = a.y; v[6] = a.z; v[7] = a.w;
            v[8] = b.x; v[9] = b.y; v[10] = b.z;
        } else {
#pragma unroll
            for (int k = 0; k < 11; ++k) v[k] = 0.f;
        }
#pragma unroll
        for (int m = 16; m; m >>= 1)
#pragma unroll
            for (int k = 0; k < 11; ++k) v[k] += __shfl_xor(v[k], m, 64);
        if (tid == 0) {
            float inv = 1.0f / v[0];
#pragma unroll
            for (int k = 0; k < 10; ++k) evf[k] = v[k + 1] * inv;
        }
    }
    __syncthreads();
    if (tid < PRED) {
        float o = b_out[tid];
#pragma unroll
        for (int k = 0; k < NQ; ++k) o = fmaf(W_out[tid * NQ + k], evf[k], o);
        out[(size_t)row * PRED + tid] = o;
    }
}

extern "C" void kernel_launch(void* const* d_in, const int* in_sizes, int n_in,
                              void* d_out, int out_size, void* d_ws, size_t ws_size,
                              hipStream_t stream) {
    const float* x     = (const float*)d_in[0];
    const float* W_in  = (const float*)d_in[1];
    const float* b_in  = (const float*)d_in[2];
    const float* qw    = (const float*)d_in[3];
    const float* W_out = (const float*)d_in[4];
    const float* b_out = (const float*)d_in[5];
    float* out = (float*)d_out;

    char* w = (char*)d_ws;
    ushort_t* Crt_r = (ushort_t*)w;                         // 1 MB
    ushort_t* Crt_i = (ushort_t*)(w + (1u << 20));          // 1 MB
    float* dr = (float*)(w + 2 * (1u << 20));               // 4 KB
    float* di = dr + DIM;                                   // 4 KB
    float* part = (float*)(w + 3 * (1u << 20));             // 4096*32*8*4 = 4 MB

    circuit_cols_kernel<<<SEQ + 1, 512, 0, stream>>>(W_in, b_in, qw, Crt_r, Crt_i, dr, di);
    dim3 g2(NROWS / GBM, DIM / GBNC);
    gemm_fused_kernel<<<g2, 256, 0, stream>>>(x, Crt_r, Crt_i, dr, di, part);
    finalize_kernel<<<NROWS, 128, 0, stream>>>(part, W_out, b_out, out);
}